// Round 3
// baseline (463.589 us; speedup 1.0000x reference)
//
#include <hip/hip_runtime.h>
#include <math.h>

// Problem constants (from reference)
#define T_TOK 4096
#define D_DIM 2048
#define NEXP  64
#define CAP   160            // floor(2*1.25*4096/64)=160, even, >=4

#define NGB   1024           // blocks: each = 1 GEMM wave (4 tokens) + 7 fill waves

typedef float vfloat4 __attribute__((ext_vector_type(4)));

// ---------------------------------------------------------------------------
// Kernel 1 (wave-specialized): every block has 8 waves.
//   wave 0  : GEMM for 4 tokens, full K per wave (lane = expert), then
//             in-wave top-2 butterfly + softmax -> topi/topw. No barriers.
//   waves 1-7: grid-strided nontemporal zero-fill of the 335.5 MB output.
// Fill stores flow from cycle 0 in every block -> HBM write BW saturated for
// the whole kernel; GEMM (~8 us of VALU + L2 reads) hides underneath.
// ---------------------------------------------------------------------------
__global__ __launch_bounds__(512) void fused_main(
    const float* __restrict__ x, const float* __restrict__ wg,
    float* __restrict__ out, int out_size,
    int* __restrict__ topi, float* __restrict__ topw)
{
    const int tid  = threadIdx.x;
    const int w    = __builtin_amdgcn_readfirstlane(tid >> 6);   // wave id
    const int lane = tid & 63;
    const int bid  = blockIdx.x;

    if (w != 0) {
        // ---- zero-fill path (7 waves/block x 1024 blocks) ----
        const int fw = bid * 7 + (w - 1);                 // 0..7167
        const size_t n4 = (size_t)out_size >> 2;          // out_size % 4 == 0
        vfloat4* o4 = (vfloat4*)out;
        const vfloat4 z = {0.f, 0.f, 0.f, 0.f};
        const size_t stride = (size_t)7 * NGB * 64;       // 458752
        for (size_t i = (size_t)fw * 64 + lane; i < n4; i += stride)
            __builtin_nontemporal_store(z, &o4[i]);
        return;
    }

    // ---- GEMM path: wave 0, lane = expert, 4 tokens, full K ----
    const int e    = lane;
    const int tok0 = bid * 4;
    float acc[4] = {0.f, 0.f, 0.f, 0.f};

    const vfloat4* __restrict__ wrow = (const vfloat4*)(wg + (size_t)e * D_DIM);

    for (int c = 0; c < D_DIM / 32; ++c) {                // 64 chunks of 32 k
        vfloat4 b[8];
#pragma unroll
        for (int j = 0; j < 8; ++j)
            b[j] = wrow[c * 8 + j];
#pragma unroll
        for (int t = 0; t < 4; ++t) {
            // wave-uniform address -> scalar-cache loads
            const vfloat4* __restrict__ xv =
                (const vfloat4*)(x + (size_t)(tok0 + t) * D_DIM) + c * 8;
            float s = 0.f;
#pragma unroll
            for (int j = 0; j < 8; ++j) {
                const vfloat4 xa = xv[j];
                s += xa.x * b[j].x + xa.y * b[j].y + xa.z * b[j].z + xa.w * b[j].w;
            }
            acc[t] += s;
        }
    }

    // top-2 + softmax per token via 6-step xor-butterfly (lane = expert).
    // Tie-break: lower index wins (matches jax.lax.top_k). Verified exact in R2.
#pragma unroll
    for (int t = 0; t < 4; ++t) {
        float v1 = acc[t];    int i1 = e;
        float v2 = -INFINITY; int i2 = NEXP;
#pragma unroll
        for (int off = 32; off >= 1; off >>= 1) {
            const float ov1 = __shfl_xor(v1, off, 64);
            const int   oi1 = __shfl_xor(i1, off, 64);
            const float ov2 = __shfl_xor(v2, off, 64);
            const int   oi2 = __shfl_xor(i2, off, 64);
            const bool firstMine = (v1 > ov1) || (v1 == ov1 && i1 < oi1);
            const float n1  = firstMine ? v1  : ov1;
            const int   ni1 = firstMine ? i1  : oi1;
            const float c1  = firstMine ? ov1 : v1;    // loser of the firsts
            const int   ci1 = firstMine ? oi1 : i1;
            const float c2  = firstMine ? v2  : ov2;   // winner's second
            const int   ci2 = firstMine ? i2  : oi2;
            const bool secondC1 = (c1 > c2) || (c1 == c2 && ci1 < ci2);
            v1 = n1;                 i1 = ni1;
            v2 = secondC1 ? c1 : c2; i2 = secondC1 ? ci1 : ci2;
        }
        if (e == 0) {
            const int gt = tok0 + t;
            const float r  = expf(v2 - v1);        // <= 1
            const float s1 = 1.0f / (1.0f + r);
            topi[2 * gt + 0] = i1;
            topi[2 * gt + 1] = i2;
            topw[2 * gt + 0] = s1;
            topw[2 * gt + 1] = r * s1;
        }
    }
}

// ---------------------------------------------------------------------------
// Kernel 2: parallel capacity assignment. Block e (64 blocks x 1 wave) owns
// expert e. Lane j scans attempts f in [j*128, j*128+128) (int4 loads),
// builds a 128-bit match mask, wave prefix-scans the counts, then walks set
// bits in ascending-f order assigning slots -- exactly the sequential
// first-come-first-served semantics, parallel over experts.
// ---------------------------------------------------------------------------
__global__ __launch_bounds__(64) void scatter_par(
    const int* __restrict__ topi, const float* __restrict__ topw,
    float* __restrict__ out)
{
    const int e    = blockIdx.x;     // expert
    const int lane = threadIdx.x;

    const int4* __restrict__ tp = (const int4*)topi + lane * 32;  // 128 ints/lane

    unsigned long long m0 = 0ull, m1 = 0ull;
#pragma unroll
    for (int i = 0; i < 16; ++i) {
        const int4 a = tp[i];
        unsigned long long bits =
              (unsigned long long)(a.x == e)
            | ((unsigned long long)(a.y == e) << 1)
            | ((unsigned long long)(a.z == e) << 2)
            | ((unsigned long long)(a.w == e) << 3);
        m0 |= bits << (i * 4);
    }
#pragma unroll
    for (int i = 16; i < 32; ++i) {
        const int4 a = tp[i];
        unsigned long long bits =
              (unsigned long long)(a.x == e)
            | ((unsigned long long)(a.y == e) << 1)
            | ((unsigned long long)(a.z == e) << 2)
            | ((unsigned long long)(a.w == e) << 3);
        m1 |= bits << ((i - 16) * 4);
    }

    const int c = __popcll(m0) + __popcll(m1);

    // inclusive shuffle scan over 64 lanes
    int v = c;
#pragma unroll
    for (int off = 1; off < 64; off <<= 1) {
        const int n = __shfl_up(v, off, 64);
        if (lane >= off) v += n;
    }
    int running = v - c;                       // exclusive prefix (global, in f order)
    const int total = __shfl(v, 63, 64);

    float* __restrict__ cb   = out + NEXP;
    float* __restrict__ mask = out + NEXP + (size_t)T_TOK * NEXP * CAP;

    const int fbase = lane * 128;
    unsigned long long mm = m0;
#pragma unroll
    for (int half = 0; half < 2; ++half) {
        while (mm) {
            const int b = __builtin_ctzll(mm);
            mm &= mm - 1;
            const int f = fbase + half * 64 + b;
            const int slot = running++;
            if (slot < CAP) {
                const size_t off = ((size_t)(f >> 1) * NEXP + e) * CAP + slot;
                cb[off]   = topw[f];
                mask[off] = 1.0f;
            }
        }
        mm = m1;
    }

    if (lane == 0)
        out[e] = (float)(total < CAP ? total : CAP);   // used_capacity
}

// ---------------------------------------------------------------------------
extern "C" void kernel_launch(void* const* d_in, const int* in_sizes, int n_in,
                              void* d_out, int out_size, void* d_ws, size_t ws_size,
                              hipStream_t stream)
{
    const float* x  = (const float*)d_in[0];   // [4096, 2048]
    const float* wg = (const float*)d_in[1];   // [64, 2048]
    float* out = (float*)d_out;

    // workspace: 8192 ints (top indices) + 8192 floats (top weights) = 64 KB
    int*   topi = (int*)d_ws;
    float* topw = (float*)(topi + T_TOK * 2);

    fused_main<<<NGB, 512, 0, stream>>>(x, wg, out, out_size, topi, topw);
    scatter_par<<<64, 64, 0, stream>>>(topi, topw, out);
}